// Round 13
// baseline (621.029 us; speedup 1.0000x reference)
//
#include <hip/hip_runtime.h>

#define ND 128   // node feature dim D
#define ED 32    // edge radial basis dim
#define LN_EPS 1e-5f

// ---------------------------------------------------------------------------
// Detect int64-vs-int32 edge_index, convert to int32 ctr/ngh, histogram ctr.
// ---------------------------------------------------------------------------
__global__ void conv_hist_kernel(const unsigned* __restrict__ raw,
                                 int* __restrict__ ctr, int* __restrict__ ngh,
                                 int* __restrict__ cnt, int E) {
    __shared__ int s_is64;
    if (threadIdx.x == 0) {
        unsigned acc = 0;
        for (int i = 1; i < 512; i += 2) acc |= raw[i];
        s_is64 = (acc == 0) ? 1 : 0;
    }
    __syncthreads();
    const int is64 = s_is64;
    const int tid = blockIdx.x * blockDim.x + threadIdx.x;
    const int stride = gridDim.x * blockDim.x;
    if (is64) {
        for (int e = tid; e < E; e += stride) {
            const int c = (int)raw[(size_t)2 * e];
            ctr[e] = c;
            ngh[e] = (int)raw[(size_t)2 * E + (size_t)2 * e];
            atomicAdd(&cnt[c], 1);
        }
    } else {
        for (int e = tid; e < E; e += stride) {
            const int c = (int)raw[e];
            ctr[e] = c;
            ngh[e] = (int)raw[(size_t)E + e];
            atomicAdd(&cnt[c], 1);
        }
    }
}

// ---------------------------------------------------------------------------
// Single-block exclusive scan over cnt[0..N) -> base[0..N]; zero cur[].
// ---------------------------------------------------------------------------
__global__ __launch_bounds__(1024) void scan_kernel(
    const int* __restrict__ cnt, int* __restrict__ base,
    int* __restrict__ cur, int N) {
    __shared__ int part[1024];
    const int tid = threadIdx.x;
    const int chunk = (N + 1023) >> 10;
    const int lo = tid * chunk;
    const int hi = min(lo + chunk, N);
    int s = 0;
    for (int i = lo; i < hi; ++i) { s += cnt[i]; cur[i] = 0; }
    part[tid] = s;
    __syncthreads();
    for (int off = 1; off < 1024; off <<= 1) {
        int v = 0;
        if (tid >= off) v = part[tid - off];
        __syncthreads();
        part[tid] += v;
        __syncthreads();
    }
    int excl = (tid > 0) ? part[tid - 1] : 0;
    for (int i = lo; i < hi; ++i) { base[i] = excl; excl += cnt[i]; }
    if (tid == 1023) base[N] = part[1023];
}

// ---------------------------------------------------------------------------
// Scatter edges into center-sorted order as int2 (edge_id, neighbor).
// ---------------------------------------------------------------------------
__global__ void scatter_kernel(const int* __restrict__ ctr,
                               const int* __restrict__ ngh,
                               const int* __restrict__ base,
                               int* __restrict__ cur,
                               int2* __restrict__ epair, int E) {
    const int tid = blockIdx.x * blockDim.x + threadIdx.x;
    const int stride = gridDim.x * blockDim.x;
    for (int e = tid; e < E; e += stride) {
        const int c = ctr[e];
        const int pos = base[c] + atomicAdd(&cur[c], 1);
        epair[pos] = make_int2(e, ngh[e]);
    }
}

// ---------------------------------------------------------------------------
// wcc = W_center_node @ W_concat[0:128, :]
// ---------------------------------------------------------------------------
__global__ void wcc_kernel(const float* __restrict__ Wc,
                           const float* __restrict__ Wcat,
                           float* __restrict__ wcc) {
    const int i = blockIdx.x;
    const int j = threadIdx.x;
    float acc = 0.f;
    for (int k = 0; k < ND; ++k)
        acc += Wc[i * ND + k] * Wcat[k * ND + j];
    wcc[i * ND + j] = acc;
}

// ---------------------------------------------------------------------------
// out[M,128] = A[M,128] @ W[128,128], fp32. (round-8 proven)
// ---------------------------------------------------------------------------
__global__ __launch_bounds__(512, 4) void gemm128_kernel(
    const float* __restrict__ A, const float* __restrict__ W,
    float* __restrict__ out, int M) {
    __shared__ float Ws[ND * ND];
    {
        float4* d = (float4*)Ws;
        const float4* s = (const float4*)W;
        for (int i = threadIdx.x; i < (ND * ND) / 4; i += 512) d[i] = s[i];
    }
    __syncthreads();
    const int slot = (int)(threadIdx.x >> 5);    // 0..15
    const int j0 = ((int)threadIdx.x & 31) * 4;
    const int rbase = blockIdx.x * 64 + slot * 4;
    const int r0 = (rbase + 0 < M) ? rbase + 0 : M - 1;
    const int r1 = (rbase + 1 < M) ? rbase + 1 : M - 1;
    const int r2 = (rbase + 2 < M) ? rbase + 2 : M - 1;
    const int r3 = (rbase + 3 < M) ? rbase + 3 : M - 1;
    const float* ap0 = A + (size_t)r0 * ND;
    const float* ap1 = A + (size_t)r1 * ND;
    const float* ap2 = A + (size_t)r2 * ND;
    const float* ap3 = A + (size_t)r3 * ND;
    float4 acc0 = {0,0,0,0}, acc1 = {0,0,0,0};
    float4 acc2 = {0,0,0,0}, acc3 = {0,0,0,0};
#pragma unroll 2
    for (int c = 0; c < 32; ++c) {
        const float4 a0 = *(const float4*)(ap0 + c * 4);
        const float4 a1 = *(const float4*)(ap1 + c * 4);
        const float4 a2 = *(const float4*)(ap2 + c * 4);
        const float4 a3 = *(const float4*)(ap3 + c * 4);
#pragma unroll
        for (int kk = 0; kk < 4; ++kk) {
            const float4 w = *(const float4*)&Ws[(c * 4 + kk) * ND + j0];
            const float x0 = ((const float*)&a0)[kk];
            const float x1 = ((const float*)&a1)[kk];
            const float x2 = ((const float*)&a2)[kk];
            const float x3 = ((const float*)&a3)[kk];
            acc0.x += x0 * w.x; acc0.y += x0 * w.y;
            acc0.z += x0 * w.z; acc0.w += x0 * w.w;
            acc1.x += x1 * w.x; acc1.y += x1 * w.y;
            acc1.z += x1 * w.z; acc1.w += x1 * w.w;
            acc2.x += x2 * w.x; acc2.y += x2 * w.y;
            acc2.z += x2 * w.z; acc2.w += x2 * w.w;
            acc3.x += x3 * w.x; acc3.y += x3 * w.y;
            acc3.z += x3 * w.z; acc3.w += x3 * w.w;
        }
    }
    if (rbase + 0 < M) *(float4*)&out[(size_t)r0 * ND + j0] = acc0;
    if (rbase + 1 < M) *(float4*)&out[(size_t)r1 * ND + j0] = acc1;
    if (rbase + 2 < M) *(float4*)&out[(size_t)r2 * ND + j0] = acc2;
    if (rbase + 3 < M) *(float4*)&out[(size_t)r3 * ND + j0] = acc3;
}

// ---------------------------------------------------------------------------
// Segmented edge reduction v6: same control flow as round 12 (proven), but
// ea fetched through the VECTOR memory path instead of SMEM. Rationale:
// rounds 7/8/12 all plateau at 165-210 µs with VALUBusy<=37% because random
// s_loads share the per-CU scalar cache (few outstanding misses) and SMEM
// only supports wait-ALL lgkmcnt(0). VMEM has deep miss queues, in-order
// returns, and the compiler emits counted vmcnt(N) before first use, so the
// A/B ping-pong genuinely overlaps. Per edge: 8 broadcast float4 (same-addr
// across the wave = single line fetch) + 1 coalesced P float2. No SMEM, no
// readlane, no DS ops. float2 arithmetic kept pairable for v_pk_fma_f32.
// ---------------------------------------------------------------------------
__device__ __forceinline__ void vload_ea(const float* __restrict__ ea_row,
                                         const float* __restrict__ P,
                                         int n, int j0,
                                         float4 (&av)[8], float2& pr) {
#pragma unroll
    for (int i = 0; i < 8; ++i) av[i] = ((const float4*)ea_row)[i];  // bcast
    pr = *(const float2*)&P[(size_t)n * ND + j0];                    // coal.
}

__device__ __forceinline__ void vfma(const float4 (&av)[8], const float2& pr,
                                     const float2 (&w)[ED], float2& acc) {
    float2 r0 = {0.f, 0.f}, r1 = {0.f, 0.f};
#pragma unroll
    for (int k = 0; k < ED; k += 2) {
        const float a0 = ((const float*)av)[k];       // static component
        const float a1 = ((const float*)av)[k + 1];
        r0.x += a0 * w[k].x;     r0.y += a0 * w[k].y;
        r1.x += a1 * w[k + 1].x; r1.y += a1 * w[k + 1].y;
    }
    acc.x += (r0.x + r1.x) * pr.x;
    acc.y += (r0.y + r1.y) * pr.y;
}

__global__ __launch_bounds__(256) void seg_kernel(
    const int* __restrict__ base, const int2* __restrict__ epair,
    const float* __restrict__ edge_attr, const float* __restrict__ W_edge,
    const float* __restrict__ P, float* __restrict__ m, int N) {
    const int lane = (int)threadIdx.x & 63;
    const int j0 = lane * 2;
    float2 w[ED];
#pragma unroll
    for (int k = 0; k < ED; ++k) {
        w[k] = *(const float2*)&W_edge[k * ND + j0];
        asm volatile("" : "+v"(w[k].x), "+v"(w[k].y));  // discourage remat
    }
    const int wid = blockIdx.x * 4 + ((int)threadIdx.x >> 6);
    const int wstride = gridDim.x * 4;
    for (int v = wid; v < N; v += wstride) {
        const int s = base[v], t = base[v + 1];   // wave-uniform
        float2 acc = {0.f, 0.f};
        int p = s, rem = t - s;
        int2 eA = make_int2(0, 0), eB = make_int2(0, 0);
        float4 avA[8], avB[8];
        float2 prA = {0.f, 0.f}, prB = {0.f, 0.f};
        if (rem >= 1) {
            eA = epair[p];
            vload_ea(edge_attr + (size_t)eA.x * ED, P, eA.y, j0, avA, prA);
        }
        if (rem >= 2) eB = epair[p + 1];
        while (rem >= 2) {
            vload_ea(edge_attr + (size_t)eB.x * ED, P, eB.y, j0, avB, prB);
            int2 eN = eA;
            if (rem >= 3) eN = epair[p + 2];      // prefetch next index
            vfma(avA, prA, w, acc);               // compiler waits A only
            if (rem >= 3) {
                eA = eN;
                vload_ea(edge_attr + (size_t)eA.x * ED, P, eA.y, j0, avA, prA);
                int2 eN2 = eB;
                if (rem >= 4) eN2 = epair[p + 3];
                vfma(avB, prB, w, acc);
                eB = eN2;
                p += 2; rem -= 2;
            } else {
                vfma(avB, prB, w, acc);
                p += 2; rem -= 2;                 // rem==0, exit
            }
        }
        if (rem == 1) vfma(avA, prA, w, acc);     // A valid: preamble/rotation
        *(float2*)&m[(size_t)v * ND + j0] = acc;
    }
}

// ---------------------------------------------------------------------------
// out[r] = LayerNorm(C2[r] + m[r] @ W_bot) * lnw + lnb  (round-8 proven)
// ---------------------------------------------------------------------------
__global__ __launch_bounds__(512, 4) void final_kernel(
    const float* __restrict__ C2, const float* __restrict__ m,
    const float* __restrict__ Wb, const float* __restrict__ lnw,
    const float* __restrict__ lnb, float* __restrict__ out, int N) {
    __shared__ float Ws[ND * ND];
    {
        float4* d = (float4*)Ws;
        const float4* s = (const float4*)Wb;
        for (int i = threadIdx.x; i < (ND * ND) / 4; i += 512) d[i] = s[i];
    }
    __syncthreads();
    const int slot = (int)(threadIdx.x >> 5);
    const int j0 = ((int)threadIdx.x & 31) * 4;
    const int rbase = blockIdx.x * 64 + slot * 4;
    const int r0 = (rbase + 0 < N) ? rbase + 0 : N - 1;
    const int r1 = (rbase + 1 < N) ? rbase + 1 : N - 1;
    const int r2 = (rbase + 2 < N) ? rbase + 2 : N - 1;
    const int r3 = (rbase + 3 < N) ? rbase + 3 : N - 1;
    const float* ap0 = m + (size_t)r0 * ND;
    const float* ap1 = m + (size_t)r1 * ND;
    const float* ap2 = m + (size_t)r2 * ND;
    const float* ap3 = m + (size_t)r3 * ND;
    float4 acc0 = {0,0,0,0}, acc1 = {0,0,0,0};
    float4 acc2 = {0,0,0,0}, acc3 = {0,0,0,0};
#pragma unroll 2
    for (int c = 0; c < 32; ++c) {
        const float4 a0 = *(const float4*)(ap0 + c * 4);
        const float4 a1 = *(const float4*)(ap1 + c * 4);
        const float4 a2 = *(const float4*)(ap2 + c * 4);
        const float4 a3 = *(const float4*)(ap3 + c * 4);
#pragma unroll
        for (int kk = 0; kk < 4; ++kk) {
            const float4 w = *(const float4*)&Ws[(c * 4 + kk) * ND + j0];
            const float x0 = ((const float*)&a0)[kk];
            const float x1 = ((const float*)&a1)[kk];
            const float x2 = ((const float*)&a2)[kk];
            const float x3 = ((const float*)&a3)[kk];
            acc0.x += x0 * w.x; acc0.y += x0 * w.y;
            acc0.z += x0 * w.z; acc0.w += x0 * w.w;
            acc1.x += x1 * w.x; acc1.y += x1 * w.y;
            acc1.z += x1 * w.z; acc1.w += x1 * w.w;
            acc2.x += x2 * w.x; acc2.y += x2 * w.y;
            acc2.z += x2 * w.z; acc2.w += x2 * w.w;
            acc3.x += x3 * w.x; acc3.y += x3 * w.y;
            acc3.z += x3 * w.z; acc3.w += x3 * w.w;
        }
    }
    const float4 w4 = *(const float4*)&lnw[j0];
    const float4 b4 = *(const float4*)&lnb[j0];
#define LN_ROW(ACC, RQ, VALID)                                               \
    {                                                                        \
        const float4 c2 = *(const float4*)&C2[(size_t)(RQ) * ND + j0];       \
        float4 h = {ACC.x + c2.x, ACC.y + c2.y, ACC.z + c2.z, ACC.w + c2.w}; \
        float sum = h.x + h.y + h.z + h.w;                                   \
        sum += __shfl_xor(sum, 16); sum += __shfl_xor(sum, 8);               \
        sum += __shfl_xor(sum, 4);  sum += __shfl_xor(sum, 2);               \
        sum += __shfl_xor(sum, 1);                                           \
        const float mean = sum * (1.f / ND);                                 \
        const float4 dd = {h.x - mean, h.y - mean, h.z - mean, h.w - mean};  \
        float qv = dd.x * dd.x + dd.y * dd.y + dd.z * dd.z + dd.w * dd.w;    \
        qv += __shfl_xor(qv, 16); qv += __shfl_xor(qv, 8);                   \
        qv += __shfl_xor(qv, 4);  qv += __shfl_xor(qv, 2);                   \
        qv += __shfl_xor(qv, 1);                                             \
        const float rstd = rsqrtf(qv * (1.f / ND) + LN_EPS);                 \
        if (VALID) {                                                         \
            float4 o;                                                        \
            o.x = dd.x * rstd * w4.x + b4.x;                                 \
            o.y = dd.y * rstd * w4.y + b4.y;                                 \
            o.z = dd.z * rstd * w4.z + b4.z;                                 \
            o.w = dd.w * rstd * w4.w + b4.w;                                 \
            *(float4*)&out[(size_t)(RQ) * ND + j0] = o;                      \
        }                                                                    \
    }
    LN_ROW(acc0, r0, rbase + 0 < N)
    LN_ROW(acc1, r1, rbase + 1 < N)
    LN_ROW(acc2, r2, rbase + 2 < N)
    LN_ROW(acc3, r3, rbase + 3 < N)
#undef LN_ROW
}

// ---------------------------------------------------------------------------
extern "C" void kernel_launch(void* const* d_in, const int* in_sizes, int n_in,
                              void* d_out, int out_size, void* d_ws, size_t ws_size,
                              hipStream_t stream) {
    const float*    node_attr = (const float*)d_in[0];
    const float*    edge_attr = (const float*)d_in[1];
    const unsigned* edge_idx  = (const unsigned*)d_in[2];
    const float*    W_node    = (const float*)d_in[3];
    const float*    W_center  = (const float*)d_in[4];
    const float*    W_concat  = (const float*)d_in[5];
    const float*    W_edge    = (const float*)d_in[6];
    const float*    lnw       = (const float*)d_in[7];
    const float*    lnb       = (const float*)d_in[8];
    float* out = (float*)d_out;

    const int N = in_sizes[0] / ND;   // 50000
    const int E = in_sizes[1] / ED;   // 800000

    // Workspace layout (round-8 proven, ~68 MB):
    char* ws = (char*)d_ws;
    float* wcc   = (float*)ws;                          // 16384 f
    float* P     = (float*)(ws + 65536);                // [N,128]
    float* m     = P + (size_t)N * ND;                  // [N,128]
    int*   ctr   = (int*)(m + (size_t)N * ND);          // [E]
    int*   ngh   = ctr + E;                             // [E]
    int2*  epair = (int2*)(ngh + E);                    // [E]
    int*   cnt   = (int*)(epair + E);                   // [N]
    int*   base  = cnt + N;                             // [N+1]
    int*   cur   = base + N + 1;                        // [N]

    hipMemsetAsync(cnt, 0, (size_t)N * sizeof(int), stream);
    conv_hist_kernel<<<512, 256, 0, stream>>>(edge_idx, ctr, ngh, cnt, E);
    scan_kernel<<<1, 1024, 0, stream>>>(cnt, base, cur, N);
    scatter_kernel<<<512, 256, 0, stream>>>(ctr, ngh, base, cur, epair, E);
    wcc_kernel<<<128, 128, 0, stream>>>(W_center, W_concat, wcc);
    gemm128_kernel<<<(N + 63) / 64, 512, 0, stream>>>(node_attr, W_node, P, N);
    gemm128_kernel<<<(N + 63) / 64, 512, 0, stream>>>(node_attr, wcc, out, N);
    seg_kernel<<<2048, 256, 0, stream>>>(base, epair, edge_attr, W_edge,
                                         P, m, N);
    final_kernel<<<(N + 63) / 64, 512, 0, stream>>>(out, m, W_concat + ND * ND,
                                                    lnw, lnb, out, N);
}

// Round 14
// 451.989 us; speedup vs baseline: 1.3740x; 1.3740x over previous
//
#include <hip/hip_runtime.h>

#define ND 128   // node feature dim D
#define ED 32    // edge radial basis dim
#define LN_EPS 1e-5f

// ---------------------------------------------------------------------------
// Histogram of center indices (int64/int32 autodetect). Histogram ONLY —
// scatter re-reads raw directly, so no ctr/ngh materialization.
// ---------------------------------------------------------------------------
__global__ void conv_hist_kernel(const unsigned* __restrict__ raw,
                                 int* __restrict__ cnt, int E) {
    __shared__ int s_is64;
    if (threadIdx.x == 0) {
        unsigned acc = 0;
        for (int i = 1; i < 512; i += 2) acc |= raw[i];
        s_is64 = (acc == 0) ? 1 : 0;
    }
    __syncthreads();
    const int is64 = s_is64;
    const int tid = blockIdx.x * blockDim.x + threadIdx.x;
    const int stride = gridDim.x * blockDim.x;
    if (is64) {
        for (int e = tid; e < E; e += stride)
            atomicAdd(&cnt[(int)raw[(size_t)2 * e]], 1);
    } else {
        for (int e = tid; e < E; e += stride)
            atomicAdd(&cnt[(int)raw[e]], 1);
    }
}

// ---------------------------------------------------------------------------
// Single-block exclusive scan over cnt[0..N) -> base[0..N]; zero cur[].
// ---------------------------------------------------------------------------
__global__ __launch_bounds__(1024) void scan_kernel(
    const int* __restrict__ cnt, int* __restrict__ base,
    int* __restrict__ cur, int N) {
    __shared__ int part[1024];
    const int tid = threadIdx.x;
    const int chunk = (N + 1023) >> 10;
    const int lo = tid * chunk;
    const int hi = min(lo + chunk, N);
    int s = 0;
    for (int i = lo; i < hi; ++i) { s += cnt[i]; cur[i] = 0; }
    part[tid] = s;
    __syncthreads();
    for (int off = 1; off < 1024; off <<= 1) {
        int v = 0;
        if (tid >= off) v = part[tid - off];
        __syncthreads();
        part[tid] += v;
        __syncthreads();
    }
    int excl = (tid > 0) ? part[tid - 1] : 0;
    for (int i = lo; i < hi; ++i) { base[i] = excl; excl += cnt[i]; }
    if (tid == 1023) base[N] = part[1023];
}

// ---------------------------------------------------------------------------
// Scatter edges into center-sorted order as int2 (edge_id, neighbor),
// reading edge_index raw (own is64 probe) — no ctr/ngh intermediate.
// ---------------------------------------------------------------------------
__global__ void scatter_kernel(const unsigned* __restrict__ raw,
                               const int* __restrict__ base,
                               int* __restrict__ cur,
                               int2* __restrict__ epair, int E) {
    __shared__ int s_is64;
    if (threadIdx.x == 0) {
        unsigned acc = 0;
        for (int i = 1; i < 512; i += 2) acc |= raw[i];
        s_is64 = (acc == 0) ? 1 : 0;
    }
    __syncthreads();
    const int is64 = s_is64;
    const int tid = blockIdx.x * blockDim.x + threadIdx.x;
    const int stride = gridDim.x * blockDim.x;
    if (is64) {
        for (int e = tid; e < E; e += stride) {
            const int c = (int)raw[(size_t)2 * e];
            const int n = (int)raw[(size_t)2 * E + (size_t)2 * e];
            const int pos = base[c] + atomicAdd(&cur[c], 1);
            epair[pos] = make_int2(e, n);
        }
    } else {
        for (int e = tid; e < E; e += stride) {
            const int c = (int)raw[e];
            const int n = (int)raw[(size_t)E + e];
            const int pos = base[c] + atomicAdd(&cur[c], 1);
            epair[pos] = make_int2(e, n);
        }
    }
}

// ---------------------------------------------------------------------------
// wcc = W_center_node @ W_concat[0:128, :]
// ---------------------------------------------------------------------------
__global__ void wcc_kernel(const float* __restrict__ Wc,
                           const float* __restrict__ Wcat,
                           float* __restrict__ wcc) {
    const int i = blockIdx.x;
    const int j = threadIdx.x;
    float acc = 0.f;
    for (int k = 0; k < ND; ++k)
        acc += Wc[i * ND + k] * Wcat[k * ND + j];
    wcc[i * ND + j] = acc;
}

// ---------------------------------------------------------------------------
// out[M,128] = A[M,128] @ W[128,128], fp32. (round-8 proven; runs ONCE now)
// ---------------------------------------------------------------------------
__global__ __launch_bounds__(512, 4) void gemm128_kernel(
    const float* __restrict__ A, const float* __restrict__ W,
    float* __restrict__ out, int M) {
    __shared__ float Ws[ND * ND];
    {
        float4* d = (float4*)Ws;
        const float4* s = (const float4*)W;
        for (int i = threadIdx.x; i < (ND * ND) / 4; i += 512) d[i] = s[i];
    }
    __syncthreads();
    const int slot = (int)(threadIdx.x >> 5);    // 0..15
    const int j0 = ((int)threadIdx.x & 31) * 4;
    const int rbase = blockIdx.x * 64 + slot * 4;
    const int r0 = (rbase + 0 < M) ? rbase + 0 : M - 1;
    const int r1 = (rbase + 1 < M) ? rbase + 1 : M - 1;
    const int r2 = (rbase + 2 < M) ? rbase + 2 : M - 1;
    const int r3 = (rbase + 3 < M) ? rbase + 3 : M - 1;
    const float* ap0 = A + (size_t)r0 * ND;
    const float* ap1 = A + (size_t)r1 * ND;
    const float* ap2 = A + (size_t)r2 * ND;
    const float* ap3 = A + (size_t)r3 * ND;
    float4 acc0 = {0,0,0,0}, acc1 = {0,0,0,0};
    float4 acc2 = {0,0,0,0}, acc3 = {0,0,0,0};
#pragma unroll 2
    for (int c = 0; c < 32; ++c) {
        const float4 a0 = *(const float4*)(ap0 + c * 4);
        const float4 a1 = *(const float4*)(ap1 + c * 4);
        const float4 a2 = *(const float4*)(ap2 + c * 4);
        const float4 a3 = *(const float4*)(ap3 + c * 4);
#pragma unroll
        for (int kk = 0; kk < 4; ++kk) {
            const float4 w = *(const float4*)&Ws[(c * 4 + kk) * ND + j0];
            const float x0 = ((const float*)&a0)[kk];
            const float x1 = ((const float*)&a1)[kk];
            const float x2 = ((const float*)&a2)[kk];
            const float x3 = ((const float*)&a3)[kk];
            acc0.x += x0 * w.x; acc0.y += x0 * w.y;
            acc0.z += x0 * w.z; acc0.w += x0 * w.w;
            acc1.x += x1 * w.x; acc1.y += x1 * w.y;
            acc1.z += x1 * w.z; acc1.w += x1 * w.w;
            acc2.x += x2 * w.x; acc2.y += x2 * w.y;
            acc2.z += x2 * w.z; acc2.w += x2 * w.w;
            acc3.x += x3 * w.x; acc3.y += x3 * w.y;
            acc3.z += x3 * w.z; acc3.w += x3 * w.w;
        }
    }
    if (rbase + 0 < M) *(float4*)&out[(size_t)r0 * ND + j0] = acc0;
    if (rbase + 1 < M) *(float4*)&out[(size_t)r1 * ND + j0] = acc1;
    if (rbase + 2 < M) *(float4*)&out[(size_t)r2 * ND + j0] = acc2;
    if (rbase + 3 < M) *(float4*)&out[(size_t)r3 * ND + j0] = acc3;
}

// ---------------------------------------------------------------------------
// Segmented edge reduction (round-12 proven: SMEM pair + reg pipeline).
// ---------------------------------------------------------------------------
typedef __attribute__((ext_vector_type(16))) int ivec16;

__device__ __forceinline__ void sload_ea(const float* p, ivec16& lo, ivec16& hi) {
    asm volatile("s_load_dwordx16 %0, %2, 0x0\n\t"
                 "s_load_dwordx16 %1, %2, 0x40"
                 : "=&s"(lo), "=&s"(hi)
                 : "s"(p));
}

__device__ __forceinline__ void seg4_fma(const ivec16& lo, const ivec16& hi,
                                         const float2& pr,
                                         const float2 (&w)[ED], float2& acc) {
    float r0x = 0.f, r0y = 0.f, r1x = 0.f, r1y = 0.f;
#pragma unroll
    for (int k = 0; k < 16; k += 2) {
        const float a0 = __int_as_float(lo[k]);
        const float a1 = __int_as_float(lo[k + 1]);
        r0x += a0 * w[k].x;     r0y += a0 * w[k].y;
        r1x += a1 * w[k + 1].x; r1y += a1 * w[k + 1].y;
    }
#pragma unroll
    for (int k = 0; k < 16; k += 2) {
        const float a0 = __int_as_float(hi[k]);
        const float a1 = __int_as_float(hi[k + 1]);
        r0x += a0 * w[16 + k].x;     r0y += a0 * w[16 + k].y;
        r1x += a1 * w[16 + k + 1].x; r1y += a1 * w[16 + k + 1].y;
    }
    acc.x += (r0x + r1x) * pr.x;
    acc.y += (r0y + r1y) * pr.y;
}

__global__ __launch_bounds__(256) void seg_kernel(
    const int* __restrict__ base, const int2* __restrict__ epair,
    const float* __restrict__ edge_attr, const float* __restrict__ W_edge,
    const float* __restrict__ P, float* __restrict__ m, int N) {
    const int lane = (int)threadIdx.x & 63;
    const int j0 = lane * 2;
    float2 w[ED];
#pragma unroll
    for (int k = 0; k < ED; ++k) {
        w[k] = *(const float2*)&W_edge[k * ND + j0];
        asm volatile("" : "+v"(w[k].x), "+v"(w[k].y));
    }
    const int wid = blockIdx.x * 4 + ((int)threadIdx.x >> 6);
    const int wstride = gridDim.x * 4;
    for (int v = wid; v < N; v += wstride) {
        const int s = base[v], t = base[v + 1];   // wave-uniform
        float2 acc = {0.f, 0.f};
        int p = s, rem = t - s;
        int2 eA0 = make_int2(0, 0), eA1 = make_int2(0, 0);
        float2 prA0 = {0.f, 0.f}, prA1 = {0.f, 0.f};
        if (rem >= 1) eA0 = epair[p];
        if (rem >= 2) eA1 = epair[p + 1];
        if (rem >= 1) prA0 = *(const float2*)&P[(size_t)eA0.y * ND + j0];
        if (rem >= 2) prA1 = *(const float2*)&P[(size_t)eA1.y * ND + j0];
        while (rem >= 2) {
            int2 nB0 = eA0, nB1 = eA1;
            float2 prB0 = prA0, prB1 = prA1;
            if (rem >= 3) nB0 = epair[p + 2];
            if (rem >= 4) nB1 = epair[p + 3];
            const int e0 = __builtin_amdgcn_readfirstlane(eA0.x);
            const int e1 = __builtin_amdgcn_readfirstlane(eA1.x);
            ivec16 lo0, hi0, lo1, hi1;
            sload_ea(edge_attr + (size_t)e0 * ED, lo0, hi0);
            sload_ea(edge_attr + (size_t)e1 * ED, lo1, hi1);
            if (rem >= 3) prB0 = *(const float2*)&P[(size_t)nB0.y * ND + j0];
            if (rem >= 4) prB1 = *(const float2*)&P[(size_t)nB1.y * ND + j0];
            asm volatile("s_waitcnt lgkmcnt(0)" ::: "memory");
            __builtin_amdgcn_sched_barrier(0);
            seg4_fma(lo0, hi0, prA0, w, acc);
            seg4_fma(lo1, hi1, prA1, w, acc);
            eA0 = nB0; eA1 = nB1; prA0 = prB0; prA1 = prB1;
            p += 2; rem -= 2;
        }
        if (rem == 1) {
            const int e0 = __builtin_amdgcn_readfirstlane(eA0.x);
            ivec16 lo0, hi0;
            sload_ea(edge_attr + (size_t)e0 * ED, lo0, hi0);
            asm volatile("s_waitcnt lgkmcnt(0)" ::: "memory");
            __builtin_amdgcn_sched_barrier(0);
            seg4_fma(lo0, hi0, prA0, w, acc);
        }
        *(float2*)&m[(size_t)v * ND + j0] = acc;
    }
}

// ---------------------------------------------------------------------------
// Fused final: out[r] = LN(node_attr[r]@wcc + m[r]@W_bot).
// Two-phase K over the SAME 64 KB LDS: stage wcc -> accumulate node_attr
// part; barrier; restage W_bot -> accumulate m part; LN epilogue.
// Eliminates the separate C2 gemm dispatch + C2 write/read (51 MB).
// ---------------------------------------------------------------------------
__global__ __launch_bounds__(512, 4) void final_kernel(
    const float* __restrict__ A1,   // node_attr
    const float* __restrict__ A2,   // m
    const float* __restrict__ W1,   // wcc
    const float* __restrict__ W2,   // W_bot = W_concat + 128*128
    const float* __restrict__ lnw, const float* __restrict__ lnb,
    float* __restrict__ out, int N) {
    __shared__ float Ws[ND * ND];
    const int slot = (int)(threadIdx.x >> 5);
    const int j0 = ((int)threadIdx.x & 31) * 4;
    const int rbase = blockIdx.x * 64 + slot * 4;
    const int r0 = (rbase + 0 < N) ? rbase + 0 : N - 1;
    const int r1 = (rbase + 1 < N) ? rbase + 1 : N - 1;
    const int r2 = (rbase + 2 < N) ? rbase + 2 : N - 1;
    const int r3 = (rbase + 3 < N) ? rbase + 3 : N - 1;
    float4 acc0 = {0,0,0,0}, acc1 = {0,0,0,0};
    float4 acc2 = {0,0,0,0}, acc3 = {0,0,0,0};

#define K_PHASE(AP, WP)                                                       \
    {                                                                         \
        {                                                                     \
            float4* d = (float4*)Ws;                                          \
            const float4* sw = (const float4*)(WP);                           \
            for (int i = threadIdx.x; i < (ND * ND) / 4; i += 512)            \
                d[i] = sw[i];                                                 \
        }                                                                     \
        __syncthreads();                                                      \
        const float* ap0 = (AP) + (size_t)r0 * ND;                            \
        const float* ap1 = (AP) + (size_t)r1 * ND;                            \
        const float* ap2 = (AP) + (size_t)r2 * ND;                            \
        const float* ap3 = (AP) + (size_t)r3 * ND;                            \
        _Pragma("unroll 2")                                                   \
        for (int c = 0; c < 32; ++c) {                                        \
            const float4 a0 = *(const float4*)(ap0 + c * 4);                  \
            const float4 a1 = *(const float4*)(ap1 + c * 4);                  \
            const float4 a2 = *(const float4*)(ap2 + c * 4);                  \
            const float4 a3 = *(const float4*)(ap3 + c * 4);                  \
            _Pragma("unroll")                                                 \
            for (int kk = 0; kk < 4; ++kk) {                                  \
                const float4 w = *(const float4*)&Ws[(c * 4 + kk) * ND + j0]; \
                const float x0 = ((const float*)&a0)[kk];                     \
                const float x1 = ((const float*)&a1)[kk];                     \
                const float x2 = ((const float*)&a2)[kk];                     \
                const float x3 = ((const float*)&a3)[kk];                     \
                acc0.x += x0 * w.x; acc0.y += x0 * w.y;                       \
                acc0.z += x0 * w.z; acc0.w += x0 * w.w;                       \
                acc1.x += x1 * w.x; acc1.y += x1 * w.y;                       \
                acc1.z += x1 * w.z; acc1.w += x1 * w.w;                       \
                acc2.x += x2 * w.x; acc2.y += x2 * w.y;                       \
                acc2.z += x2 * w.z; acc2.w += x2 * w.w;                       \
                acc3.x += x3 * w.x; acc3.y += x3 * w.y;                       \
                acc3.z += x3 * w.z; acc3.w += x3 * w.w;                       \
            }                                                                 \
        }                                                                     \
        __syncthreads();                                                      \
    }

    K_PHASE(A1, W1)     // C2 part: node_attr @ wcc
    K_PHASE(A2, W2)     // m @ W_bot (accumulates into same acc)
#undef K_PHASE

    const float4 w4 = *(const float4*)&lnw[j0];
    const float4 b4 = *(const float4*)&lnb[j0];
#define LN_ROW(ACC, RQ, VALID)                                               \
    {                                                                        \
        float4 h = ACC;                                                      \
        float sum = h.x + h.y + h.z + h.w;                                   \
        sum += __shfl_xor(sum, 16); sum += __shfl_xor(sum, 8);               \
        sum += __shfl_xor(sum, 4);  sum += __shfl_xor(sum, 2);               \
        sum += __shfl_xor(sum, 1);                                           \
        const float mean = sum * (1.f / ND);                                 \
        const float4 dd = {h.x - mean, h.y - mean, h.z - mean, h.w - mean};  \
        float qv = dd.x * dd.x + dd.y * dd.y + dd.z * dd.z + dd.w * dd.w;    \
        qv += __shfl_xor(qv, 16); qv += __shfl_xor(qv, 8);                   \
        qv += __shfl_xor(qv, 4);  qv += __shfl_xor(qv, 2);                   \
        qv += __shfl_xor(qv, 1);                                             \
        const float rstd = rsqrtf(qv * (1.f / ND) + LN_EPS);                 \
        if (VALID) {                                                         \
            float4 o;                                                        \
            o.x = dd.x * rstd * w4.x + b4.x;                                 \
            o.y = dd.y * rstd * w4.y + b4.y;                                 \
            o.z = dd.z * rstd * w4.z + b4.z;                                 \
            o.w = dd.w * rstd * w4.w + b4.w;                                 \
            *(float4*)&out[(size_t)(RQ) * ND + j0] = o;                      \
        }                                                                    \
    }
    LN_ROW(acc0, r0, rbase + 0 < N)
    LN_ROW(acc1, r1, rbase + 1 < N)
    LN_ROW(acc2, r2, rbase + 2 < N)
    LN_ROW(acc3, r3, rbase + 3 < N)
#undef LN_ROW
}

// ---------------------------------------------------------------------------
extern "C" void kernel_launch(void* const* d_in, const int* in_sizes, int n_in,
                              void* d_out, int out_size, void* d_ws, size_t ws_size,
                              hipStream_t stream) {
    const float*    node_attr = (const float*)d_in[0];
    const float*    edge_attr = (const float*)d_in[1];
    const unsigned* edge_idx  = (const unsigned*)d_in[2];
    const float*    W_node    = (const float*)d_in[3];
    const float*    W_center  = (const float*)d_in[4];
    const float*    W_concat  = (const float*)d_in[5];
    const float*    W_edge    = (const float*)d_in[6];
    const float*    lnw       = (const float*)d_in[7];
    const float*    lnb       = (const float*)d_in[8];
    float* out = (float*)d_out;

    const int N = in_sizes[0] / ND;   // 50000
    const int E = in_sizes[1] / ED;   // 800000

    // Workspace layout (~62 MB; ctr/ngh eliminated):
    char* ws = (char*)d_ws;
    float* wcc   = (float*)ws;                          // 16384 f
    float* P     = (float*)(ws + 65536);                // [N,128]
    float* m     = P + (size_t)N * ND;                  // [N,128]
    int2*  epair = (int2*)(m + (size_t)N * ND);         // [E]
    int*   cnt   = (int*)(epair + E);                   // [N]
    int*   base  = cnt + N;                             // [N+1]
    int*   cur   = base + N + 1;                        // [N]

    hipMemsetAsync(cnt, 0, (size_t)N * sizeof(int), stream);
    conv_hist_kernel<<<512, 256, 0, stream>>>(edge_idx, cnt, E);
    scan_kernel<<<1, 1024, 0, stream>>>(cnt, base, cur, N);
    scatter_kernel<<<512, 256, 0, stream>>>(edge_idx, base, cur, epair, E);
    wcc_kernel<<<128, 128, 0, stream>>>(W_center, W_concat, wcc);
    gemm128_kernel<<<(N + 63) / 64, 512, 0, stream>>>(node_attr, W_node, P, N);
    seg_kernel<<<2048, 256, 0, stream>>>(base, epair, edge_attr, W_edge,
                                         P, m, N);
    final_kernel<<<(N + 63) / 64, 512, 0, stream>>>(node_attr, m, wcc,
                                                    W_concat + ND * ND,
                                                    lnw, lnb, out, N);
}